// Round 10
// baseline (288.740 us; speedup 1.0000x reference)
//
#include <hip/hip_runtime.h>
#include <cstdint>
#include <cstddef>

// InterpAttentionKHeadsNet — round 10: weight-resident waves, barrier-light.
// Budget model (r6 counters): per CU, L2 weight reads ~64us > LDS ~52us >>
// MFMA ~15us; wall 192us => latency-bound with L2 weights the top demand.
// Design: 512-thr block = 8 waves; wave owns a 32-ch octant; W2+W3 resident
// in 128 VGPR (f16x8[16] x2, static-indexed; MFMA A reads VGPRs on gfx950).
// Two groups of 4 queries ping-pong through 4x33KB LDS buffers (135KB,
// 1 blk/CU): each layer reads buf[in], writes buf[out] -> ONE barrier/layer,
// 5 barriers per 8 queries (r6: 8 per 4). Each segment has 2 independent
// group-GEMMs (4 indep MFMA chains) to hide ds_read latency at low TLP.
// W1 (17-ks, rel folded) + Wq streamed from L2 (L2-hot, ~5us agg).
// Q/S/softmax wave-local (wave w -> group w>>2, query w&3), r9-verified code.
// Tripwires: WRITE_SIZE >> 156KB or VGPR_Count > 230 => regalloc overflow.

#define NLAT 256
#define KNB 16
#define QB 8           // queries per block: 2 groups x 4
#define ROWB 528       // 264 f16: 256 ch + rel(3)+zeros(5) at bytes 512..527
#define GBUF 33792     // 64 rows * ROWB
#define MTSTR 16896    // 32 * ROWB

typedef float    f32x4  __attribute__((ext_vector_type(4)));
typedef float    f32x16 __attribute__((ext_vector_type(16)));
typedef _Float16 f16x8  __attribute__((ext_vector_type(8)));
typedef _Float16 f16x4  __attribute__((ext_vector_type(4)));

extern "C" __global__ __launch_bounds__(512, 2)
void interp_mfma(const float* __restrict__ latents,
                 const float* __restrict__ pts,
                 const float* __restrict__ ptsq,
                 const void*  __restrict__ proj,
                 const unsigned short* __restrict__ Lt_u,   // fp16 [B][N][256]
                 const unsigned short* __restrict__ W1p,    // 17-ks pack
                 const unsigned short* __restrict__ W2p,    // 16-ks pack
                 const unsigned short* __restrict__ W3p,
                 const unsigned short* __restrict__ Wqh,    // fp16 [64][256] row-major
                 const float* __restrict__ b1, const float* __restrict__ b2,
                 const float* __restrict__ b3, const float* __restrict__ bq,
                 const float* __restrict__ wv8, const float* __restrict__ c0p,
                 float* __restrict__ out,
                 int N, int NQ, int use_lt)
{
  __shared__ unsigned char buf[4 * GBUF];   // 135,168 B -> 1 block/CU
  const int tid = threadIdx.x;
  const int bid = blockIdx.x;
  const int lane = tid & 63, wave = tid >> 6;
  const int lm32 = lane & 31, h = lane >> 5;

  // int64/int32 probe (uniform -> scalar loads)
  int is64;
  {
    const int* p = (const int*)proj;
    int z = 1;
    for (int i = 0; i < 64; ++i) z &= (p[2 * i + 1] == 0);
    is64 = z;
  }

  // ---- resident weights: wave's 32-ch octant of W2, W3 (64+64 VGPR) ----
  const char* w2base = (const char*)W2p + (wave * 32 + lm32) * 32 + h * 16;
  const char* w3base = (const char*)W3p + (wave * 32 + lm32) * 32 + h * 16;
  f16x8 w2r[16], w3r[16];
#pragma unroll
  for (int ks = 0; ks < 16; ++ks) {
    w2r[ks] = *(const f16x8*)(w2base + ks * 8192);
    w3r[ks] = *(const f16x8*)(w3base + ks * 8192);
  }

  // ---- gather: 128 rows (2 groups x 64), 4 threads/row x 128B ----
  {
    const int row = tid & 127, part = tid >> 7;      // part 0..3
    const long long gq = (long long)bid * QB + (row >> 4);
    const long long pb = gq * KNB + (row & 15);
    const int id = is64 ? (int)((const long long*)proj)[pb]
                        : ((const int*)proj)[pb];
    const int b = (int)(gq / NQ);
    const int grp = row >> 6, r64 = row & 63;
    char* dst = (char*)buf + grp * 2 * GBUF + r64 * 528 + part * 128;
    if (use_lt) {
      const _Float16* src = (const _Float16*)Lt_u + ((size_t)b * N + id) * NLAT + part * 64;
#pragma unroll
      for (int cc = 0; cc < 8; ++cc)
        *(f16x8*)(dst + cc * 16) = *(const f16x8*)(src + cc * 8);
    } else {
      for (int cc = 0; cc < 8; ++cc) {
        f16x8 v;
#pragma unroll
        for (int e = 0; e < 8; ++e)
          v[e] = (_Float16)latents[((size_t)b * NLAT + part * 64 + cc * 8 + e) * N + id];
        *(f16x8*)(dst + cc * 16) = v;
      }
    }
    if (part == 0) {  // k 256..263 at bytes 512..527 (rel + zeros)
      const int nq = (int)(gq - (long long)b * NQ);
      f16x8 v = {0, 0, 0, 0, 0, 0, 0, 0};
#pragma unroll
      for (int j = 0; j < 3; ++j)
        v[j] = (_Float16)(ptsq[((size_t)b * 3 + j) * NQ + nq]
                        - pts[((size_t)b * 3 + j) * N + id]);
      *(f16x8*)((char*)buf + grp * 2 * GBUF + r64 * 528 + 512) = v;
    }
  }
  __syncthreads();

  // B-frag row bases per group (ping-pong offsets added per layer)
  const char* bpA = (const char*)buf + lm32 * 528 + h * 16;            // group A buffers 0/1
  const char* bpB = (const char*)buf + 2 * GBUF + lm32 * 528 + h * 16; // group B buffers 2/3

  // epilogue helper expressed inline per layer (static indices only)
#define EPILOGUE(ACC, OUTA, OUTB, BIAS, RELU)                                   \
  {                                                                             \
    _Pragma("unroll")                                                           \
    for (int qq = 0; qq < 4; ++qq) {                                            \
      const int ch0 = wave * 32 + qq * 8 + h * 4;                               \
      const float4 bs = *(const float4*)((BIAS) + ch0);                         \
      const float bb[4] = {bs.x, bs.y, bs.z, bs.w};                             \
      _Pragma("unroll")                                                         \
      for (int g = 0; g < 2; ++g) {                                             \
        _Pragma("unroll")                                                       \
        for (int mt = 0; mt < 2; ++mt) {                                        \
          f16x4 v;                                                              \
          _Pragma("unroll")                                                     \
          for (int j = 0; j < 4; ++j) {                                         \
            float x = ACC[g][mt][qq * 4 + j] + bb[j];                           \
            if (RELU) x = fmaxf(x, 0.f);                                        \
            v[j] = (_Float16)x;                                                 \
          }                                                                     \
          *(f16x4*)((g ? (OUTB) : (OUTA)) + (mt * 32 + lm32) * 528 + ch0 * 2) = v; \
        }                                                                       \
      }                                                                         \
    }                                                                           \
  }

  // ---- Layer 1: streamed A (17 ks, rel tail folded), in buf0 -> out buf1 ----
  {
    const char* w1base = (const char*)W1p + (wave * 32 + lm32) * 32 + h * 16;
    f32x16 acc[2][2];
#pragma unroll
    for (int g = 0; g < 2; ++g)
#pragma unroll
      for (int mt = 0; mt < 2; ++mt) acc[g][mt] = (f32x16)(0.f);
#pragma unroll
    for (int ks = 0; ks < 17; ++ks) {
      f16x8 a = *(const f16x8*)(w1base + ks * 8192);
      f16x8 bb[2][2];
      if (ks == 16) {
        const f16x8 z = {0, 0, 0, 0, 0, 0, 0, 0};
#pragma unroll
        for (int g = 0; g < 2; ++g)
#pragma unroll
          for (int mt = 0; mt < 2; ++mt) {
            f16x8 t_ = *(const f16x8*)((g ? bpB : bpA) - h * 16 + mt * MTSTR + 512);
            bb[g][mt] = (h == 0) ? t_ : z;
          }
      } else {
#pragma unroll
        for (int g = 0; g < 2; ++g)
#pragma unroll
          for (int mt = 0; mt < 2; ++mt)
            bb[g][mt] = *(const f16x8*)((g ? bpB : bpA) + mt * MTSTR + ks * 32);
      }
#pragma unroll
      for (int g = 0; g < 2; ++g)
#pragma unroll
        for (int mt = 0; mt < 2; ++mt)
          acc[g][mt] = __builtin_amdgcn_mfma_f32_32x32x16_f16(a, bb[g][mt], acc[g][mt], 0, 0, 0);
    }
    EPILOGUE(acc, (char*)buf + GBUF, (char*)buf + 3 * GBUF, b1, true);
  }
  __syncthreads();

  // ---- Layer 2: resident w2r, in buf1 -> out buf0 ----
  {
    f32x16 acc[2][2];
#pragma unroll
    for (int g = 0; g < 2; ++g)
#pragma unroll
      for (int mt = 0; mt < 2; ++mt) acc[g][mt] = (f32x16)(0.f);
#pragma unroll
    for (int ks = 0; ks < 16; ++ks) {
      f16x8 bb[2][2];
#pragma unroll
      for (int g = 0; g < 2; ++g)
#pragma unroll
        for (int mt = 0; mt < 2; ++mt)
          bb[g][mt] = *(const f16x8*)((g ? bpB : bpA) + GBUF + mt * MTSTR + ks * 32);
#pragma unroll
      for (int g = 0; g < 2; ++g)
#pragma unroll
        for (int mt = 0; mt < 2; ++mt)
          acc[g][mt] = __builtin_amdgcn_mfma_f32_32x32x16_f16(w2r[ks], bb[g][mt], acc[g][mt], 0, 0, 0);
    }
    EPILOGUE(acc, (char*)buf, (char*)buf + 2 * GBUF, b2, true);
  }
  __syncthreads();

  // ---- Layer 3: resident w3r, in buf0 -> out buf1 ----
  {
    f32x16 acc[2][2];
#pragma unroll
    for (int g = 0; g < 2; ++g)
#pragma unroll
      for (int mt = 0; mt < 2; ++mt) acc[g][mt] = (f32x16)(0.f);
#pragma unroll
    for (int ks = 0; ks < 16; ++ks) {
      f16x8 bb[2][2];
#pragma unroll
      for (int g = 0; g < 2; ++g)
#pragma unroll
        for (int mt = 0; mt < 2; ++mt)
          bb[g][mt] = *(const f16x8*)((g ? bpB : bpA) + mt * MTSTR + ks * 32);
#pragma unroll
      for (int g = 0; g < 2; ++g)
#pragma unroll
        for (int mt = 0; mt < 2; ++mt)
          acc[g][mt] = __builtin_amdgcn_mfma_f32_32x32x16_f16(w3r[ks], bb[g][mt], acc[g][mt], 0, 0, 0);
    }
    EPILOGUE(acc, (char*)buf + GBUF, (char*)buf + 3 * GBUF, b3, true);
  }
  __syncthreads();

  // ---- Q/S/softmax, wave-local: wave w -> group w>>2, query w&3 ----
  const int g = wave >> 2, q = wave & 3;
  const int lm = lane & 15, lk = lane >> 4;
  const char* src = (const char*)buf + (g * 2 + 1) * GBUF;   // H3 lives in buf1
  const char* bp16 = src + (q * 16 + lm) * 528 + lk * 16;

  f32x4 qacc[4];
#pragma unroll
  for (int ht = 0; ht < 4; ++ht) qacc[ht] = (f32x4){0.f, 0.f, 0.f, 0.f};
  {
#pragma unroll
    for (int ks = 0; ks < 8; ++ks) {
      f16x8 b = *(const f16x8*)(bp16 + ks * 64);
#pragma unroll
      for (int ht = 0; ht < 4; ++ht) {  // A row = head ht*16+lm
        f16x8 a = *(const f16x8*)((const char*)Wqh + (ht * 16 + lm) * 512 + ks * 64 + lk * 16);
        qacc[ht] = __builtin_amdgcn_mfma_f32_16x16x32_f16(a, b, qacc[ht], 0, 0, 0);
      }
    }
  }

  // S[row] = wv8 . H3[row], row = q*16+lm of this group
  float sv;
  {
    float sacc = 0.f;
#pragma unroll
    for (int cc = 0; cc < 8; ++cc) {
      f16x8 v = *(const f16x8*)(bp16 + cc * 64);
      const int k0 = cc * 32 + lk * 8;
      const float4 w0 = *(const float4*)(wv8 + k0);
      const float4 w1 = *(const float4*)(wv8 + k0 + 4);
      sacc += (float)v[0] * w0.x + (float)v[1] * w0.y
            + (float)v[2] * w0.z + (float)v[3] * w0.w;
      sacc += (float)v[4] * w1.x + (float)v[5] * w1.y
            + (float)v[6] * w1.z + (float)v[7] * w1.w;
    }
    sacc += __shfl_xor(sacc, 16);
    sacc += __shfl_xor(sacc, 32);
    sv = sacc;
  }

  // softmax over nb (= lm lanes) per head; mean over 64 heads; output
  {
    float sw = 0.f;
#pragma unroll
    for (int ht = 0; ht < 4; ++ht) {
      const float4 bv4 = *(const float4*)(bq + ht * 16 + lk * 4);
      const float bqv[4] = {bv4.x, bv4.y, bv4.z, bv4.w};
#pragma unroll
      for (int r = 0; r < 4; ++r) {
        const float qv = qacc[ht][r] + bqv[r];
        float mx = qv;
#pragma unroll
        for (int msk = 1; msk < 16; msk <<= 1) mx = fmaxf(mx, __shfl_xor(mx, msk));
        const float e = __expf(qv - mx);
        float s = e;
#pragma unroll
        for (int msk = 1; msk < 16; msk <<= 1) s += __shfl_xor(s, msk);
        sw += e / s;
      }
    }
    sw += __shfl_xor(sw, 16);
    sw += __shfl_xor(sw, 32);
    float val = sw * (1.f / 64.f) * sv;
#pragma unroll
    for (int msk = 1; msk < 16; msk <<= 1) val += __shfl_xor(val, msk);
    if (lane == 0) out[(long long)bid * QB + g * 4 + q] = val + c0p[0];
  }
#undef EPILOGUE
}

// ---- prep: fp32 -> fp16 packs (W1p = 17 ks incl. rel tail); wv8/c0 folds ----
extern "C" __global__ void prep_w(const float* __restrict__ W1, const float* __restrict__ W2,
                                  const float* __restrict__ W3, const float* __restrict__ Wq,
                                  const float* __restrict__ Wv, const float* __restrict__ W8,
                                  const float* __restrict__ bv, const float* __restrict__ b8,
                                  unsigned short* W1p, unsigned short* W2p,
                                  unsigned short* W3p, unsigned short* Wqh,
                                  float* wv8, float* c0) {
  const int t = blockIdx.x * 256 + threadIdx.x;
  union { _Float16 h; unsigned short u; } cv;
  if (t < 69632) {   // W1p: ks = t>>12, ch = (t>>4)&255, he = t&15
    const int ks = t >> 12, ch = (t >> 4) & 255, he = t & 15;
    const int k = ks * 16 + he;
    cv.h = (k < 259) ? (_Float16)W1[(size_t)ch * 259 + k] : (_Float16)0.f;
    W1p[t] = cv.u;
  }
  if (t < 65536) {
    const int ch = t >> 8, k = t & 255;
    const int dst = (k >> 4) * 4096 + ch * 16 + (k & 15);
    cv.h = (_Float16)W2[t]; W2p[dst] = cv.u;
    cv.h = (_Float16)W3[t]; W3p[dst] = cv.u;
  }
  if (t < 16384) { cv.h = (_Float16)Wq[t]; Wqh[t] = cv.u; }  // row-major
  if (t < 256) {
    float s = 0.f;
    for (int o = 0; o < 256; ++o) s += Wv[(size_t)o * 256 + t] * W8[o];
    wv8[t] = s;
  }
  if (t == 0) {
    float s = 0.f;
    for (int o = 0; o < 256; ++o) s += bv[o] * W8[o];
    c0[0] = s + b8[0];
  }
}

// ---- transpose latents [B][256][N] -> fp16 [B][N][256] ----
extern "C" __global__ void transp(const float* __restrict__ latents,
                                  unsigned short* __restrict__ Lt, int N) {
  __shared__ unsigned short tile[256][68];
  const int b = blockIdx.y, n0 = blockIdx.x * 64, tid = threadIdx.x;
  const int nl = tid & 63;
  union { _Float16 h; unsigned short u; } cv;
  for (int c = tid >> 6; c < 256; c += 4) {
    const int n = n0 + nl;
    float v = (n < N) ? latents[((size_t)b * NLAT + c) * N + n] : 0.f;
    cv.h = (_Float16)v;
    tile[c][nl] = cv.u;
  }
  __syncthreads();
  const int nr = tid >> 2, cg = (tid & 3) * 64;
  const int n = n0 + nr;
  if (n < N) {
    for (int cc = 0; cc < 64; cc += 8) {
      f16x8 v;
#pragma unroll
      for (int j = 0; j < 8; ++j) {
        union { unsigned short u; _Float16 h; } bk;
        bk.u = tile[cg + cc + j][nr];
        v[j] = bk.h;
      }
      *(f16x8*)((_Float16*)Lt + ((size_t)b * N + n) * NLAT + cg + cc) = v;
    }
  }
}

extern "C" void kernel_launch(void* const* d_in, const int* in_sizes, int n_in,
                              void* d_out, int out_size, void* d_ws, size_t ws_size,
                              hipStream_t stream) {
  (void)n_in; (void)out_size;
  const float* latents = (const float*)d_in[0];
  const float* pts     = (const float*)d_in[1];
  const float* ptsq    = (const float*)d_in[2];
  const void*  proj    = d_in[3];
  const float* W1 = (const float*)d_in[4];  const float* b1 = (const float*)d_in[5];
  const float* W2 = (const float*)d_in[6];  const float* b2 = (const float*)d_in[7];
  const float* W3 = (const float*)d_in[8];  const float* b3 = (const float*)d_in[9];
  const float* Wq = (const float*)d_in[10]; const float* bq = (const float*)d_in[11];
  const float* Wv = (const float*)d_in[12]; const float* bv = (const float*)d_in[13];
  const float* W8 = (const float*)d_in[14]; const float* b8 = (const float*)d_in[15];
  float* out = (float*)d_out;

  const int B  = 2;
  const int N  = in_sizes[1] / (3 * B);
  const int NQ = in_sizes[2] / (3 * B);

  size_t off = 0;
  auto alloc = [&](size_t bytes) -> char* {
    char* p = (char*)d_ws + off;
    off += (bytes + 255) & ~(size_t)255;
    return p;
  };
  unsigned short* W1p = (unsigned short*)alloc(69632 * 2);   // 17-ks pack
  unsigned short* W2p = (unsigned short*)alloc(65536 * 2);
  unsigned short* W3p = (unsigned short*)alloc(65536 * 2);
  unsigned short* Wqh = (unsigned short*)alloc(16384 * 2);
  float* wv8 = (float*)alloc(256 * 4);
  float* c0  = (float*)alloc(4);
  const size_t lt_bytes = (size_t)B * N * NLAT * 2;
  unsigned short* Lt = (unsigned short*)((char*)d_ws + off);
  const int use_lt = (off + lt_bytes <= ws_size) ? 1 : 0;

  hipLaunchKernelGGL(prep_w, dim3(272), dim3(256), 0, stream,
                     W1, W2, W3, Wq, Wv, W8, bv, b8, W1p, W2p, W3p, Wqh, wv8, c0);
  if (use_lt)
    hipLaunchKernelGGL(transp, dim3((N + 63) / 64, B), dim3(256), 0, stream,
                       latents, Lt, N);
  const int nblocks = (B * NQ + QB - 1) / QB;   // 2500
  hipLaunchKernelGGL(interp_mfma, dim3(nblocks), dim3(512), 0, stream,
                     latents, pts, ptsq, proj, Lt, W1p, W2p, W3p, Wqh,
                     b1, b2, b3, bq, wv8, c0, out, N, NQ, use_lt);
}

// Round 11
// 259.846 us; speedup vs baseline: 1.1112x; 1.1112x over previous
//
#include <hip/hip_runtime.h>
#include <cstdint>
#include <cstddef>

// InterpAttentionKHeadsNet — round 11: r6 structure + half-layer A-burst.
// Plateau diagnosis (r6-r10): per-ks critical path = L2 A-load ~200cy +
// LDS ~120cy + 32cy MFMA => per-wave duty ~9%, x4 waves/SIMD = the measured
// ~33% MfmaUtil. Fix the per-iteration L2 latency: load each half-layer's
// 16 A-frags in one fully-static burst (64 VGPR scoped array) -> one ~200cy
// wait per half, compiler's fine-grained vmcnt lets MFMA(ks) overlap
// remaining loads. (256,3) gives the register headroom r6 lacked (it sat at
// exactly the 128 cap). Wave-local Q/S/softmax (r9-proven) kills 4 barriers.
// ROWB 560 (r6's proven layout). 3 blk/CU, 12 waves/CU.
// Tripwires: WRITE_SIZE >> 156KB = spill; MfmaUtil <= 35 = compiler defeated
// the burst (then the 2-barrier structure's ceiling is ~190us and r6 stands).

#define NLAT 256
#define KNB 16
#define QB 4
#define MROWS 64       // QB*KNB rows per block
#define ROWB 560       // 35 granules * 16B: 256 ch + rel/zeros + pad
#define MTSTR 17920    // 32*ROWB

typedef float    f32x4  __attribute__((ext_vector_type(4)));
typedef float    f32x16 __attribute__((ext_vector_type(16)));
typedef _Float16 f16x8  __attribute__((ext_vector_type(8)));
typedef _Float16 f16x4  __attribute__((ext_vector_type(4)));

// In-place layer: wave computes C'[64ch x 64m] via 2x2 tiles of 32x32x16.
// A-frags burst-loaded per 8-ks half. Wp pack: f16 elem = ks*4096+ch*16+(k&15).
template <bool L1>
__device__ __forceinline__ void layer_burst(
    unsigned char* __restrict__ buf, const unsigned short* __restrict__ Wp,
    const float* __restrict__ bias, const float* __restrict__ W1f,
    int lane, int wave, bool relu)
{
  const int lm32 = lane & 31, h = lane >> 5;
  // B-frag: row = mt*32+lm32, k = ks*16+h*8 -> byte = lm32*560 + h*16 + mt*MTSTR + ks*32
  const char* bp = (const char*)buf + lm32 * 560 + h * 16;
  // A-frag: ch = wave*64 + ct*32 + lm32 -> byte = ks*8192 + ch*32 + h*16
  const char* wbase = (const char*)Wp + (wave * 64 + lm32) * 32 + h * 16;

  f32x16 acc[2][2];
#pragma unroll
  for (int i = 0; i < 2; ++i)
#pragma unroll
    for (int j = 0; j < 2; ++j) acc[i][j] = (f32x16)(0.f);

  {  // ---- half 0: ks 0..7 ----
    f16x8 A[8][2];
#pragma unroll
    for (int ks = 0; ks < 8; ++ks) {
      A[ks][0] = *(const f16x8*)(wbase + ks * 8192);
      A[ks][1] = *(const f16x8*)(wbase + ks * 8192 + 1024);
    }
#pragma unroll
    for (int ks = 0; ks < 8; ++ks) {
      f16x8 b[2];
#pragma unroll
      for (int mt = 0; mt < 2; ++mt)
        b[mt] = *(const f16x8*)(bp + mt * MTSTR + ks * 32);
#pragma unroll
      for (int ct = 0; ct < 2; ++ct)
#pragma unroll
        for (int mt = 0; mt < 2; ++mt)
          acc[ct][mt] = __builtin_amdgcn_mfma_f32_32x32x16_f16(A[ks][ct], b[mt], acc[ct][mt], 0, 0, 0);
    }
  }
  {  // ---- half 1: ks 8..15 ----
    f16x8 A[8][2];
#pragma unroll
    for (int ks = 0; ks < 8; ++ks) {
      A[ks][0] = *(const f16x8*)(wbase + (ks + 8) * 8192);
      A[ks][1] = *(const f16x8*)(wbase + (ks + 8) * 8192 + 1024);
    }
#pragma unroll
    for (int ks = 0; ks < 8; ++ks) {
      f16x8 b[2];
#pragma unroll
      for (int mt = 0; mt < 2; ++mt)
        b[mt] = *(const f16x8*)(bp + mt * MTSTR + (ks + 8) * 32);
#pragma unroll
      for (int ct = 0; ct < 2; ++ct)
#pragma unroll
        for (int mt = 0; mt < 2; ++mt)
          acc[ct][mt] = __builtin_amdgcn_mfma_f32_32x32x16_f16(A[ks][ct], b[mt], acc[ct][mt], 0, 0, 0);
    }
  }
  if (L1) {  // tail k-step: k = 256..271 (rel 256-258, zeros to 271)
    f16x8 a[2], b[2];
#pragma unroll
    for (int ct = 0; ct < 2; ++ct) {
      f16x8 v = {0, 0, 0, 0, 0, 0, 0, 0};
      if (h == 0) {
        const int ch = wave * 64 + ct * 32 + lm32;
        const float* wt = W1f + (size_t)ch * 259 + 256;
        v[0] = (_Float16)wt[0]; v[1] = (_Float16)wt[1]; v[2] = (_Float16)wt[2];
      }
      a[ct] = v;
    }
#pragma unroll
    for (int mt = 0; mt < 2; ++mt)
      b[mt] = *(const f16x8*)(bp + mt * MTSTR + 512);  // h=0: rel, h=1: zeros
#pragma unroll
    for (int ct = 0; ct < 2; ++ct)
#pragma unroll
      for (int mt = 0; mt < 2; ++mt)
        acc[ct][mt] = __builtin_amdgcn_mfma_f32_32x32x16_f16(a[ct], b[mt], acc[ct][mt], 0, 0, 0);
  }
  __syncthreads();  // all reads done -> safe to overwrite in place
  // C layout (32x32): col m = lane&31, ch-row = j + 8q + 4h.
#pragma unroll
  for (int ct = 0; ct < 2; ++ct) {
#pragma unroll
    for (int q = 0; q < 4; ++q) {
      const int ch0 = wave * 64 + ct * 32 + q * 8 + h * 4;
      const float4 bs = *(const float4*)(bias + ch0);
      const float bb[4] = {bs.x, bs.y, bs.z, bs.w};
#pragma unroll
      for (int mt = 0; mt < 2; ++mt) {
        f16x4 v;
#pragma unroll
        for (int j = 0; j < 4; ++j) {
          float x = acc[ct][mt][q * 4 + j] + bb[j];
          if (relu) x = fmaxf(x, 0.f);
          v[j] = (_Float16)x;
        }
        *(f16x4*)((char*)buf + (mt * 32 + lm32) * 560 + ch0 * 2) = v;
      }
    }
  }
}

extern "C" __global__ __launch_bounds__(256, 3)
void interp_mfma(const float* __restrict__ latents,
                 const float* __restrict__ pts,
                 const float* __restrict__ ptsq,
                 const void*  __restrict__ proj,
                 const unsigned short* __restrict__ Lt_u,   // fp16 [B][N][256]
                 const float* __restrict__ W1f,             // fp32 [256][259]
                 const unsigned short* __restrict__ W1p,
                 const unsigned short* __restrict__ W2p,
                 const unsigned short* __restrict__ W3p,
                 const unsigned short* __restrict__ Wqh,    // fp16 [64][256] row-major
                 const float* __restrict__ b1, const float* __restrict__ b2,
                 const float* __restrict__ b3, const float* __restrict__ bq,
                 const float* __restrict__ wv8, const float* __restrict__ c0p,
                 float* __restrict__ out,
                 int N, int NQ, int use_lt)
{
  __shared__ unsigned char buf[MROWS * ROWB];  // 35,840 B -> 3 blk/CU at (256,3)
  const int tid = threadIdx.x;
  const int bid = blockIdx.x;
  const int lane = tid & 63, wave = tid >> 6;
  const int lm = lane & 15, lk = lane >> 4;

  // int64/int32 probe (uniform -> scalar loads)
  int is64;
  {
    const int* p = (const int*)proj;
    int z = 1;
    for (int i = 0; i < 64; ++i) z &= (p[2 * i + 1] == 0);
    is64 = z;
  }

  // ---- gather: thread (row = tid&63, part = tid>>6) fills ch part*64..+63
  {
    const int row = tid & 63, part = tid >> 6;
    const long long g = (long long)bid * QB + (row >> 4);
    const long long pbase = g * KNB + (row & 15);
    const int id = is64 ? (int)((const long long*)proj)[pbase]
                        : ((const int*)proj)[pbase];
    const int b = (int)(g / NQ);
    char* dst = (char*)buf + row * 560 + part * 128;
    if (use_lt) {
      const _Float16* src = (const _Float16*)Lt_u + ((size_t)b * N + id) * NLAT + part * 64;
#pragma unroll
      for (int cc = 0; cc < 8; ++cc)
        *(f16x8*)(dst + cc * 16) = *(const f16x8*)(src + cc * 8);
    } else {
      for (int cc = 0; cc < 8; ++cc) {
        f16x8 v;
#pragma unroll
        for (int e = 0; e < 8; ++e)
          v[e] = (_Float16)latents[((size_t)b * NLAT + part * 64 + cc * 8 + e) * N + id];
        *(f16x8*)(dst + cc * 16) = v;
      }
    }
    if (part == 0) {  // tail k 256..271: rel at 512, zeros at 528
      const int nq = (int)(g - (long long)b * NQ);
      f16x8 v = {0, 0, 0, 0, 0, 0, 0, 0};
#pragma unroll
      for (int j = 0; j < 3; ++j)
        v[j] = (_Float16)(ptsq[((size_t)b * 3 + j) * NQ + nq]
                        - pts[((size_t)b * 3 + j) * N + id]);
      const f16x8 z = {0, 0, 0, 0, 0, 0, 0, 0};
      *(f16x8*)((char*)buf + row * 560 + 512) = v;
      *(f16x8*)((char*)buf + row * 560 + 528) = z;
    }
  }
  __syncthreads();

  layer_burst<true >(buf, W1p, b1, W1f, lane, wave, true);
  __syncthreads();
  layer_burst<false>(buf, W2p, b2, nullptr, lane, wave, true);
  __syncthreads();
  layer_burst<false>(buf, W3p, b3, nullptr, lane, wave, true);
  __syncthreads();

  // ---- Q heads, wave-local: wave w owns rows w*16..w*16+15 (query w)
  const char* bp16 = (const char*)buf + (wave * 16 + lm) * 560 + lk * 16;
  f32x4 qacc[4];
#pragma unroll
  for (int ht = 0; ht < 4; ++ht) qacc[ht] = (f32x4){0.f, 0.f, 0.f, 0.f};
  {
#pragma unroll
    for (int ks = 0; ks < 8; ++ks) {
      f16x8 b = *(const f16x8*)(bp16 + ks * 64);
#pragma unroll
      for (int ht = 0; ht < 4; ++ht) {  // A row = head ht*16+lm
        f16x8 a = *(const f16x8*)((const char*)Wqh + (ht * 16 + lm) * 512 + ks * 64 + lk * 16);
        qacc[ht] = __builtin_amdgcn_mfma_f32_16x16x32_f16(a, b, qacc[ht], 0, 0, 0);
      }
    }
  }

  // ---- S[row] = wv8 . H3[row], row = wave*16+lm (lk splits k; shfl reduce)
  float sv;
  {
    float sacc = 0.f;
#pragma unroll
    for (int cc = 0; cc < 8; ++cc) {
      f16x8 v = *(const f16x8*)(bp16 + cc * 64);
      const int k0 = cc * 32 + lk * 8;
      const float4 w0 = *(const float4*)(wv8 + k0);
      const float4 w1 = *(const float4*)(wv8 + k0 + 4);
      sacc += (float)v[0] * w0.x + (float)v[1] * w0.y
            + (float)v[2] * w0.z + (float)v[3] * w0.w;
      sacc += (float)v[4] * w1.x + (float)v[5] * w1.y
            + (float)v[6] * w1.z + (float)v[7] * w1.w;
    }
    sacc += __shfl_xor(sacc, 16);
    sacc += __shfl_xor(sacc, 32);
    sv = sacc;
  }

  // ---- softmax over nb (= lm lanes) per head; mean over 64 heads; output
  // C layout (16x16): col = lm = nb, head = ht*16 + lk*4 + r.
  {
    float sw = 0.f;
#pragma unroll
    for (int ht = 0; ht < 4; ++ht) {
      const float4 bv4 = *(const float4*)(bq + ht * 16 + lk * 4);
      const float bqv[4] = {bv4.x, bv4.y, bv4.z, bv4.w};
#pragma unroll
      for (int r = 0; r < 4; ++r) {
        const float qv = qacc[ht][r] + bqv[r];
        float mx = qv;
#pragma unroll
        for (int msk = 1; msk < 16; msk <<= 1) mx = fmaxf(mx, __shfl_xor(mx, msk));
        const float e = __expf(qv - mx);
        float s = e;
#pragma unroll
        for (int msk = 1; msk < 16; msk <<= 1) s += __shfl_xor(s, msk);
        sw += e / s;
      }
    }
    sw += __shfl_xor(sw, 16);   // sum over lk quarters -> all 64 heads
    sw += __shfl_xor(sw, 32);
    float val = sw * (1.f / 64.f) * sv;   // att[nb] * S[nb]
#pragma unroll
    for (int msk = 1; msk < 16; msk <<= 1) val += __shfl_xor(val, msk);
    if (lane == 0) out[(long long)bid * QB + wave] = val + c0p[0];
  }
}

// ---- prep: fp32 -> fp16 packs; wv8 = W8*Wv fold; c0 = b8 + W8.bv ----
extern "C" __global__ void prep_w(const float* __restrict__ W1, const float* __restrict__ W2,
                                  const float* __restrict__ W3, const float* __restrict__ Wq,
                                  const float* __restrict__ Wv, const float* __restrict__ W8,
                                  const float* __restrict__ bv, const float* __restrict__ b8,
                                  unsigned short* W1p, unsigned short* W2p,
                                  unsigned short* W3p, unsigned short* Wqh,
                                  float* wv8, float* c0) {
  const int t = blockIdx.x * 256 + threadIdx.x;
  union { _Float16 h; unsigned short u; } cv;
  if (t < 65536) {
    const int ch = t >> 8, k = t & 255;
    const int dst = (k >> 4) * 4096 + ch * 16 + (k & 15);  // 32x32 k-major pack
    cv.h = (_Float16)W1[(size_t)ch * 259 + k]; W1p[dst] = cv.u;
    cv.h = (_Float16)W2[t]; W2p[dst] = cv.u;
    cv.h = (_Float16)W3[t]; W3p[dst] = cv.u;
  }
  if (t < 16384) { cv.h = (_Float16)Wq[t]; Wqh[t] = cv.u; }  // row-major
  if (t < 256) {
    float s = 0.f;
    for (int o = 0; o < 256; ++o) s += Wv[(size_t)o * 256 + t] * W8[o];
    wv8[t] = s;
  }
  if (t == 0) {
    float s = 0.f;
    for (int o = 0; o < 256; ++o) s += bv[o] * W8[o];
    c0[0] = s + b8[0];
  }
}

// ---- transpose latents [B][256][N] -> fp16 [B][N][256] ----
extern "C" __global__ void transp(const float* __restrict__ latents,
                                  unsigned short* __restrict__ Lt, int N) {
  __shared__ unsigned short tile[256][68];
  const int b = blockIdx.y, n0 = blockIdx.x * 64, tid = threadIdx.x;
  const int nl = tid & 63;
  union { _Float16 h; unsigned short u; } cv;
  for (int c = tid >> 6; c < 256; c += 4) {
    const int n = n0 + nl;
    float v = (n < N) ? latents[((size_t)b * NLAT + c) * N + n] : 0.f;
    cv.h = (_Float16)v;
    tile[c][nl] = cv.u;
  }
  __syncthreads();
  const int nr = tid >> 2, cg = (tid & 3) * 64;
  const int n = n0 + nr;
  if (n < N) {
    for (int cc = 0; cc < 64; cc += 8) {
      f16x8 v;
#pragma unroll
      for (int j = 0; j < 8; ++j) {
        union { unsigned short u; _Float16 h; } bk;
        bk.u = tile[cg + cc + j][nr];
        v[j] = bk.h;
      }
      *(f16x8*)((_Float16*)Lt + ((size_t)b * N + n) * NLAT + cg + cc) = v;
    }
  }
}

extern "C" void kernel_launch(void* const* d_in, const int* in_sizes, int n_in,
                              void* d_out, int out_size, void* d_ws, size_t ws_size,
                              hipStream_t stream) {
  (void)n_in; (void)out_size;
  const float* latents = (const float*)d_in[0];
  const float* pts     = (const float*)d_in[1];
  const float* ptsq    = (const float*)d_in[2];
  const void*  proj    = d_in[3];
  const float* W1 = (const float*)d_in[4];  const float* b1 = (const float*)d_in[5];
  const float* W2 = (const float*)d_in[6];  const float* b2 = (const float*)d_in[7];
  const float* W3 = (const float*)d_in[8];  const float* b3 = (const float*)d_in[9];
  const float* Wq = (const float*)d_in[10]; const float* bq = (const float*)d_in[11];
  const float* Wv = (const float*)d_in[12]; const float* bv = (const float*)d_in[13];
  const float* W8 = (const float*)d_in[14]; const float* b8 = (const float*)d_in[15];
  float* out = (float*)d_out;

  const int B  = 2;
  const int N  = in_sizes[1] / (3 * B);
  const int NQ = in_sizes[2] / (3 * B);

  size_t off = 0;
  auto alloc = [&](size_t bytes) -> char* {
    char* p = (char*)d_ws + off;
    off += (bytes + 255) & ~(size_t)255;
    return p;
  };
  unsigned short* W1p = (unsigned short*)alloc(65536 * 2);
  unsigned short* W2p = (unsigned short*)alloc(65536 * 2);
  unsigned short* W3p = (unsigned short*)alloc(65536 * 2);
  unsigned short* Wqh = (unsigned short*)alloc(16384 * 2);
  float* wv8 = (float*)alloc(256 * 4);
  float* c0  = (float*)alloc(4);
  const size_t lt_bytes = (size_t)B * N * NLAT * 2;
  unsigned short* Lt = (unsigned short*)((char*)d_ws + off);
  const int use_lt = (off + lt_bytes <= ws_size) ? 1 : 0;

  hipLaunchKernelGGL(prep_w, dim3(256), dim3(256), 0, stream,
                     W1, W2, W3, Wq, Wv, W8, bv, b8, W1p, W2p, W3p, Wqh, wv8, c0);
  if (use_lt)
    hipLaunchKernelGGL(transp, dim3((N + 63) / 64, B), dim3(256), 0, stream,
                       latents, Lt, N);
  const int nblocks = (B * NQ + QB - 1) / QB;   // 5000
  hipLaunchKernelGGL(interp_mfma, dim3(nblocks), dim3(256), 0, stream,
                     latents, pts, ptsq, proj, Lt, W1, W1p, W2p, W3p, Wqh,
                     b1, b2, b3, bq, wv8, c0, out, N, NQ, use_lt);
}

// Round 12
// 256.050 us; speedup vs baseline: 1.1277x; 1.0148x over previous
//
#include <hip/hip_runtime.h>
#include <cstdint>
#include <cstddef>

// InterpAttentionKHeadsNet — round 12: EXACT r6 base (best: 192us) + ONE
// isolated delta: wave-local Q/S/softmax + inline per-thread id probe.
// Deletes sidx/Sp/Sv LDS and 3 barriers (10 -> 7). Everything else verbatim
// r6: QB=4, 256 thr, (256,4), ROWB 560, plain 32x32x16 layer loop, fp32 W1
// tail, 4 blk/CU (LDS 35.8KB, regs 64+64acc = exactly 128).
// Rationale: r6-r11 showed perf ~ blocks/CU (hard-capped at 4) and barrier
// drains serialize three ~30% pipe demands; this removes barriers without
// touching occupancy. r9/r11's regressions traced to (256,3) occupancy loss
// + compiler-defeated prefetch, NOT to the wave-local epilogue (verified
// correct since r8, absmax identical).

#define NLAT 256
#define KNB 16
#define QB 4
#define MROWS 64       // QB*KNB rows per block
#define ROWB 560       // 35 granules * 16B: 256 ch + rel/zeros + pad
#define MTSTR 17920    // 32*ROWB

typedef float    f32x4  __attribute__((ext_vector_type(4)));
typedef float    f32x16 __attribute__((ext_vector_type(16)));
typedef _Float16 f16x8  __attribute__((ext_vector_type(8)));
typedef _Float16 f16x4  __attribute__((ext_vector_type(4)));

// In-place layer: wave computes C'[64ch x 64m] via 2x2 tiles of 32x32x16.
// Wp pack: f16 elem = ks*4096 + ch*16 + (k&15).
__device__ __forceinline__ void layer_mfma32(
    unsigned char* __restrict__ buf, const unsigned short* __restrict__ Wp,
    const float* __restrict__ bias, const float* __restrict__ W1f,
    int lane, int wave, bool relu)
{
  const int lm32 = lane & 31, h = lane >> 5;
  // B-frag: row = mt*32+lm32, k = ks*16+h*8 -> byte = lm32*560 + h*16 + mt*MTSTR + ks*32
  const char* bp = (const char*)buf + lm32 * 560 + h * 16;
  // A-frag: ch = wave*64 + ct*32 + lm32 -> byte = ks*8192 + ch*32 + h*16
  const char* wbase = (const char*)Wp + (wave * 64 + lm32) * 32 + h * 16;

  f32x16 acc[2][2];
#pragma unroll
  for (int i = 0; i < 2; ++i)
#pragma unroll
    for (int j = 0; j < 2; ++j) acc[i][j] = (f32x16)(0.f);

#pragma unroll
  for (int ks = 0; ks < 16; ++ks) {
    f16x8 a[2], b[2];
#pragma unroll
    for (int ct = 0; ct < 2; ++ct)
      a[ct] = *(const f16x8*)(wbase + ks * 8192 + ct * 1024);
#pragma unroll
    for (int mt = 0; mt < 2; ++mt)
      b[mt] = *(const f16x8*)(bp + mt * MTSTR + ks * 32);
#pragma unroll
    for (int ct = 0; ct < 2; ++ct)
#pragma unroll
      for (int mt = 0; mt < 2; ++mt)
        acc[ct][mt] = __builtin_amdgcn_mfma_f32_32x32x16_f16(a[ct], b[mt], acc[ct][mt], 0, 0, 0);
  }
  if (W1f) {  // tail k-step: k = 256..271 (rel 256-258, zeros to 271)
    f16x8 a[2], b[2];
#pragma unroll
    for (int ct = 0; ct < 2; ++ct) {
      f16x8 v = {0, 0, 0, 0, 0, 0, 0, 0};
      if (h == 0) {
        const int ch = wave * 64 + ct * 32 + lm32;
        const float* wt = W1f + (size_t)ch * 259 + 256;
        v[0] = (_Float16)wt[0]; v[1] = (_Float16)wt[1]; v[2] = (_Float16)wt[2];
      }
      a[ct] = v;
    }
#pragma unroll
    for (int mt = 0; mt < 2; ++mt)
      b[mt] = *(const f16x8*)(bp + mt * MTSTR + 512);  // h=0: rel, h=1: zeros
#pragma unroll
    for (int ct = 0; ct < 2; ++ct)
#pragma unroll
      for (int mt = 0; mt < 2; ++mt)
        acc[ct][mt] = __builtin_amdgcn_mfma_f32_32x32x16_f16(a[ct], b[mt], acc[ct][mt], 0, 0, 0);
  }
  __syncthreads();  // all reads done -> safe to overwrite in place
  // C layout (32x32): col m = lane&31, ch-row = j + 8q + 4h.
#pragma unroll
  for (int ct = 0; ct < 2; ++ct) {
#pragma unroll
    for (int q = 0; q < 4; ++q) {
      const int ch0 = wave * 64 + ct * 32 + q * 8 + h * 4;
      const float4 bs = *(const float4*)(bias + ch0);
      const float bb[4] = {bs.x, bs.y, bs.z, bs.w};
#pragma unroll
      for (int mt = 0; mt < 2; ++mt) {
        f16x4 v;
#pragma unroll
        for (int j = 0; j < 4; ++j) {
          float x = acc[ct][mt][q * 4 + j] + bb[j];
          if (relu) x = fmaxf(x, 0.f);
          v[j] = (_Float16)x;
        }
        *(f16x4*)((char*)buf + (mt * 32 + lm32) * 560 + ch0 * 2) = v;
      }
    }
  }
}

extern "C" __global__ __launch_bounds__(256, 4)
void interp_mfma(const float* __restrict__ latents,
                 const float* __restrict__ pts,
                 const float* __restrict__ ptsq,
                 const void*  __restrict__ proj,
                 const unsigned short* __restrict__ Lt_u,   // fp16 [B][N][256]
                 const float* __restrict__ W1f,             // fp32 [256][259]
                 const unsigned short* __restrict__ W1p,
                 const unsigned short* __restrict__ W2p,
                 const unsigned short* __restrict__ W3p,
                 const unsigned short* __restrict__ Wqh,    // fp16 [64][256] row-major
                 const float* __restrict__ b1, const float* __restrict__ b2,
                 const float* __restrict__ b3, const float* __restrict__ bq,
                 const float* __restrict__ wv8, const float* __restrict__ c0p,
                 float* __restrict__ out,
                 int N, int NQ, int use_lt)
{
  __shared__ unsigned char buf[MROWS * ROWB];  // 35,840 B -> 4 blk/CU
  const int tid = threadIdx.x;
  const int bid = blockIdx.x;
  const int lane = tid & 63, wave = tid >> 6;
  const int lm = lane & 15, lk = lane >> 4;

  // inline int64/int32 probe (uniform -> scalar loads; no barrier)
  int is64;
  {
    const int* p = (const int*)proj;
    int z = 1;
    for (int i = 0; i < 64; ++i) z &= (p[2 * i + 1] == 0);
    is64 = z;
  }

  // ---- gather: thread (row = tid&63, part = tid>>6) fills ch part*64..+63
  {
    const int row = tid & 63, part = tid >> 6;
    const long long g = (long long)bid * QB + (row >> 4);
    const long long pbase = g * KNB + (row & 15);
    const int id = is64 ? (int)((const long long*)proj)[pbase]
                        : ((const int*)proj)[pbase];
    const int b = (int)(g / NQ);
    char* dst = (char*)buf + row * 560 + part * 128;
    if (use_lt) {
      const _Float16* src = (const _Float16*)Lt_u + ((size_t)b * N + id) * NLAT + part * 64;
#pragma unroll
      for (int cc = 0; cc < 8; ++cc)
        *(f16x8*)(dst + cc * 16) = *(const f16x8*)(src + cc * 8);
    } else {
      for (int cc = 0; cc < 8; ++cc) {
        f16x8 v;
#pragma unroll
        for (int e = 0; e < 8; ++e)
          v[e] = (_Float16)latents[((size_t)b * NLAT + part * 64 + cc * 8 + e) * N + id];
        *(f16x8*)(dst + cc * 16) = v;
      }
    }
    if (part == 0) {  // tail k 256..271: rel at bytes 512, zeros at 528
      const int nq = (int)(g - (long long)b * NQ);
      f16x8 v = {0, 0, 0, 0, 0, 0, 0, 0};
#pragma unroll
      for (int j = 0; j < 3; ++j)
        v[j] = (_Float16)(ptsq[((size_t)b * 3 + j) * NQ + nq]
                        - pts[((size_t)b * 3 + j) * N + id]);
      const f16x8 z = {0, 0, 0, 0, 0, 0, 0, 0};
      *(f16x8*)((char*)buf + row * 560 + 512) = v;
      *(f16x8*)((char*)buf + row * 560 + 528) = z;
    }
  }
  __syncthreads();

  layer_mfma32(buf, W1p, b1, W1f, lane, wave, true);
  __syncthreads();
  layer_mfma32(buf, W2p, b2, nullptr, lane, wave, true);
  __syncthreads();
  layer_mfma32(buf, W3p, b3, nullptr, lane, wave, true);
  __syncthreads();

  // ---- Q heads, wave-local: wave w owns rows w*16..w*16+15 (query w)
  // B-frag: row = w*16+lm, k = ks*32+lk*8 -> byte = row*560 + ks*64 + lk*16
  const char* bp16 = (const char*)buf + (wave * 16 + lm) * 560 + lk * 16;
  f32x4 qacc[4];
#pragma unroll
  for (int ht = 0; ht < 4; ++ht) qacc[ht] = (f32x4){0.f, 0.f, 0.f, 0.f};
  {
#pragma unroll
    for (int ks = 0; ks < 8; ++ks) {
      f16x8 b = *(const f16x8*)(bp16 + ks * 64);
#pragma unroll
      for (int ht = 0; ht < 4; ++ht) {  // A row = head ht*16+lm
        f16x8 a = *(const f16x8*)((const char*)Wqh + (ht * 16 + lm) * 512 + ks * 64 + lk * 16);
        qacc[ht] = __builtin_amdgcn_mfma_f32_16x16x32_f16(a, b, qacc[ht], 0, 0, 0);
      }
    }
  }

  // ---- S[row] = wv8 . H3[row], row = wave*16+lm (lk splits k; shfl reduce)
  float sv;
  {
    float sacc = 0.f;
#pragma unroll
    for (int cc = 0; cc < 8; ++cc) {
      f16x8 v = *(const f16x8*)(bp16 + cc * 64);
      const int k0 = cc * 32 + lk * 8;
      const float4 w0 = *(const float4*)(wv8 + k0);
      const float4 w1 = *(const float4*)(wv8 + k0 + 4);
      sacc += (float)v[0] * w0.x + (float)v[1] * w0.y
            + (float)v[2] * w0.z + (float)v[3] * w0.w;
      sacc += (float)v[4] * w1.x + (float)v[5] * w1.y
            + (float)v[6] * w1.z + (float)v[7] * w1.w;
    }
    sacc += __shfl_xor(sacc, 16);
    sacc += __shfl_xor(sacc, 32);
    sv = sacc;
  }

  // ---- softmax over nb (= lm lanes) per head; mean over 64 heads; output
  // C layout (16x16): col = lm = nb, head = ht*16 + lk*4 + r.
  {
    float sw = 0.f;
#pragma unroll
    for (int ht = 0; ht < 4; ++ht) {
      const float4 bv4 = *(const float4*)(bq + ht * 16 + lk * 4);
      const float bqv[4] = {bv4.x, bv4.y, bv4.z, bv4.w};
#pragma unroll
      for (int r = 0; r < 4; ++r) {
        const float qv = qacc[ht][r] + bqv[r];
        float mx = qv;
#pragma unroll
        for (int msk = 1; msk < 16; msk <<= 1) mx = fmaxf(mx, __shfl_xor(mx, msk));
        const float e = __expf(qv - mx);
        float s = e;
#pragma unroll
        for (int msk = 1; msk < 16; msk <<= 1) s += __shfl_xor(s, msk);
        sw += e / s;
      }
    }
    sw += __shfl_xor(sw, 16);   // sum over lk quarters -> all 64 heads
    sw += __shfl_xor(sw, 32);
    float val = sw * (1.f / 64.f) * sv;   // att[nb] * S[nb]
#pragma unroll
    for (int msk = 1; msk < 16; msk <<= 1) val += __shfl_xor(val, msk);
    if (lane == 0) out[(long long)bid * QB + wave] = val + c0p[0];
  }
}

// ---- prep: fp32 -> fp16 packs; wv8 = W8*Wv fold; c0 = b8 + W8.bv ----
extern "C" __global__ void prep_w(const float* __restrict__ W1, const float* __restrict__ W2,
                                  const float* __restrict__ W3, const float* __restrict__ Wq,
                                  const float* __restrict__ Wv, const float* __restrict__ W8,
                                  const float* __restrict__ bv, const float* __restrict__ b8,
                                  unsigned short* W1p, unsigned short* W2p,
                                  unsigned short* W3p, unsigned short* Wqh,
                                  float* wv8, float* c0) {
  const int t = blockIdx.x * 256 + threadIdx.x;
  union { _Float16 h; unsigned short u; } cv;
  if (t < 65536) {
    const int ch = t >> 8, k = t & 255;
    const int dst = (k >> 4) * 4096 + ch * 16 + (k & 15);  // 32x32 k-major pack
    cv.h = (_Float16)W1[(size_t)ch * 259 + k]; W1p[dst] = cv.u;
    cv.h = (_Float16)W2[t]; W2p[dst] = cv.u;
    cv.h = (_Float16)W3[t]; W3p[dst] = cv.u;
  }
  if (t < 16384) { cv.h = (_Float16)Wq[t]; Wqh[t] = cv.u; }  // row-major
  if (t < 256) {
    float s = 0.f;
    for (int o = 0; o < 256; ++o) s += Wv[(size_t)o * 256 + t] * W8[o];
    wv8[t] = s;
  }
  if (t == 0) {
    float s = 0.f;
    for (int o = 0; o < 256; ++o) s += bv[o] * W8[o];
    c0[0] = s + b8[0];
  }
}

// ---- transpose latents [B][256][N] -> fp16 [B][N][256] ----
extern "C" __global__ void transp(const float* __restrict__ latents,
                                  unsigned short* __restrict__ Lt, int N) {
  __shared__ unsigned short tile[256][68];
  const int b = blockIdx.y, n0 = blockIdx.x * 64, tid = threadIdx.x;
  const int nl = tid & 63;
  union { _Float16 h; unsigned short u; } cv;
  for (int c = tid >> 6; c < 256; c += 4) {
    const int n = n0 + nl;
    float v = (n < N) ? latents[((size_t)b * NLAT + c) * N + n] : 0.f;
    cv.h = (_Float16)v;
    tile[c][nl] = cv.u;
  }
  __syncthreads();
  const int nr = tid >> 2, cg = (tid & 3) * 64;
  const int n = n0 + nr;
  if (n < N) {
    for (int cc = 0; cc < 64; cc += 8) {
      f16x8 v;
#pragma unroll
      for (int j = 0; j < 8; ++j) {
        union { unsigned short u; _Float16 h; } bk;
        bk.u = tile[cg + cc + j][nr];
        v[j] = bk.h;
      }
      *(f16x8*)((_Float16*)Lt + ((size_t)b * N + n) * NLAT + cg + cc) = v;
    }
  }
}

extern "C" void kernel_launch(void* const* d_in, const int* in_sizes, int n_in,
                              void* d_out, int out_size, void* d_ws, size_t ws_size,
                              hipStream_t stream) {
  (void)n_in; (void)out_size;
  const float* latents = (const float*)d_in[0];
  const float* pts     = (const float*)d_in[1];
  const float* ptsq    = (const float*)d_in[2];
  const void*  proj    = d_in[3];
  const float* W1 = (const float*)d_in[4];  const float* b1 = (const float*)d_in[5];
  const float* W2 = (const float*)d_in[6];  const float* b2 = (const float*)d_in[7];
  const float* W3 = (const float*)d_in[8];  const float* b3 = (const float*)d_in[9];
  const float* Wq = (const float*)d_in[10]; const float* bq = (const float*)d_in[11];
  const float* Wv = (const float*)d_in[12]; const float* bv = (const float*)d_in[13];
  const float* W8 = (const float*)d_in[14]; const float* b8 = (const float*)d_in[15];
  float* out = (float*)d_out;

  const int B  = 2;
  const int N  = in_sizes[1] / (3 * B);
  const int NQ = in_sizes[2] / (3 * B);

  size_t off = 0;
  auto alloc = [&](size_t bytes) -> char* {
    char* p = (char*)d_ws + off;
    off += (bytes + 255) & ~(size_t)255;
    return p;
  };
  unsigned short* W1p = (unsigned short*)alloc(65536 * 2);
  unsigned short* W2p = (unsigned short*)alloc(65536 * 2);
  unsigned short* W3p = (unsigned short*)alloc(65536 * 2);
  unsigned short* Wqh = (unsigned short*)alloc(16384 * 2);
  float* wv8 = (float*)alloc(256 * 4);
  float* c0  = (float*)alloc(4);
  const size_t lt_bytes = (size_t)B * N * NLAT * 2;
  unsigned short* Lt = (unsigned short*)((char*)d_ws + off);
  const int use_lt = (off + lt_bytes <= ws_size) ? 1 : 0;

  hipLaunchKernelGGL(prep_w, dim3(256), dim3(256), 0, stream,
                     W1, W2, W3, Wq, Wv, W8, bv, b8, W1p, W2p, W3p, Wqh, wv8, c0);
  if (use_lt)
    hipLaunchKernelGGL(transp, dim3((N + 63) / 64, B), dim3(256), 0, stream,
                       latents, Lt, N);
  const int nblocks = (B * NQ + QB - 1) / QB;   // 5000
  hipLaunchKernelGGL(interp_mfma, dim3(nblocks), dim3(256), 0, stream,
                     latents, pts, ptsq, proj, Lt, W1, W1p, W2p, W3p, Wqh,
                     b1, b2, b3, bq, wv8, c0, out, N, NQ, use_lt);
}

// Round 13
// 210.408 us; speedup vs baseline: 1.3723x; 1.2169x over previous
//
#include <hip/hip_runtime.h>
#include <cstdint>
#include <cstddef>

// InterpAttentionKHeadsNet — round 13: algebraic L1 fold (work removal).
// Each point is gathered ~16x (320k gathers / 20k points), and
// W1.[latent;rel] = W1_lat.latent + W1_rel.rel. Precompute L1pre[b,n,:] =
// W1_lat.latent[b,n] + b1 ONCE (l1pre kernel, 2.6 GFLOP MFMA); hot kernel
// gathers L1pre and fuses the rank-3 rel update + ReLU into the gather
// (fp32 math pre-ReLU). Deletes the per-pair L1 GEMM: per-wave MFMA 228->160,
// streamed weights 416->288 KB/block, no rel-tail. Everything else r6
// VERBATIM (r7-r12: all 7 deviations regressed): QB=4, (256,4), tid0 probe +
// sidx LDS, r6 Q/S/softmax epilogue. ROWB 528 (33 odd -> same bank property).

#define NLAT 256
#define KNB 16
#define QB 4
#define MROWS 64       // QB*KNB rows per block
#define ROWB 528       // 264 f16: 256 ch used + pad
#define MTSTR 16896    // 32*ROWB

typedef float    f32x4  __attribute__((ext_vector_type(4)));
typedef float    f32x16 __attribute__((ext_vector_type(16)));
typedef _Float16 f16x8  __attribute__((ext_vector_type(8)));
typedef _Float16 f16x4  __attribute__((ext_vector_type(4)));

struct Smem {
  unsigned char buf[MROWS * ROWB];  // 33,792 B in-place activations
  float Sp[4][MROWS];
  float Sv[MROWS];
  int sidx[MROWS];
  int is64;
};

// In-place layer (r6 body, 16 ks, no tail): wave computes C'[64ch x 64m]
// via 2x2 tiles of 32x32x16. Wp pack: f16 elem = ks*4096 + ch*16 + (k&15).
__device__ __forceinline__ void layer_mfma32(
    unsigned char* __restrict__ buf, const unsigned short* __restrict__ Wp,
    const float* __restrict__ bias, int lane, int wave, bool relu)
{
  const int lm32 = lane & 31, h = lane >> 5;
  const char* bp = (const char*)buf + lm32 * 528 + h * 16;
  const char* wbase = (const char*)Wp + (wave * 64 + lm32) * 32 + h * 16;

  f32x16 acc[2][2];
#pragma unroll
  for (int i = 0; i < 2; ++i)
#pragma unroll
    for (int j = 0; j < 2; ++j) acc[i][j] = (f32x16)(0.f);

#pragma unroll
  for (int ks = 0; ks < 16; ++ks) {
    f16x8 a[2], b[2];
#pragma unroll
    for (int ct = 0; ct < 2; ++ct)
      a[ct] = *(const f16x8*)(wbase + ks * 8192 + ct * 1024);
#pragma unroll
    for (int mt = 0; mt < 2; ++mt)
      b[mt] = *(const f16x8*)(bp + mt * MTSTR + ks * 32);
#pragma unroll
    for (int ct = 0; ct < 2; ++ct)
#pragma unroll
      for (int mt = 0; mt < 2; ++mt)
        acc[ct][mt] = __builtin_amdgcn_mfma_f32_32x32x16_f16(a[ct], b[mt], acc[ct][mt], 0, 0, 0);
  }
  __syncthreads();  // all reads done -> safe to overwrite in place
  // C layout (32x32): col m = lane&31, ch-row = j + 8q + 4h.
#pragma unroll
  for (int ct = 0; ct < 2; ++ct) {
#pragma unroll
    for (int q = 0; q < 4; ++q) {
      const int ch0 = wave * 64 + ct * 32 + q * 8 + h * 4;
      const float4 bs = *(const float4*)(bias + ch0);
      const float bb[4] = {bs.x, bs.y, bs.z, bs.w};
#pragma unroll
      for (int mt = 0; mt < 2; ++mt) {
        f16x4 v;
#pragma unroll
        for (int j = 0; j < 4; ++j) {
          float x = acc[ct][mt][q * 4 + j] + bb[j];
          if (relu) x = fmaxf(x, 0.f);
          v[j] = (_Float16)x;
        }
        *(f16x4*)((char*)buf + (mt * 32 + lm32) * 528 + ch0 * 2) = v;
      }
    }
  }
}

extern "C" __global__ __launch_bounds__(256, 4)
void interp_mfma(const float* __restrict__ pts,
                 const float* __restrict__ ptsq,
                 const void*  __restrict__ proj,
                 const unsigned short* __restrict__ L1pre,  // fp16 [B][N][256]
                 const float* __restrict__ w1rT,            // fp32 [3][256]
                 const unsigned short* __restrict__ W2p,
                 const unsigned short* __restrict__ W3p,
                 const unsigned short* __restrict__ Wqh,    // fp16 [64][256] row-major
                 const float* __restrict__ b2, const float* __restrict__ b3,
                 const float* __restrict__ bq,
                 const float* __restrict__ wv8, const float* __restrict__ c0p,
                 float* __restrict__ out,
                 int N, int NQ)
{
  __shared__ Smem sm;
  const int tid = threadIdx.x;
  const int bid = blockIdx.x;
  const int lane = tid & 63, wave = tid >> 6;
  const int lm = lane & 15, lk = lane >> 4;

  if (tid == 0) {
    const int* p = (const int*)proj;
    int z = 1;
    for (int i = 0; i < 64; ++i) z &= (p[2 * i + 1] == 0);
    sm.is64 = z;
  }
  __syncthreads();
  if (tid < MROWS) {
    long long g = (long long)bid * QB + (tid >> 4);
    long long base = g * KNB + (tid & 15);
    sm.sidx[tid] = sm.is64 ? (int)((const long long*)proj)[base]
                           : ((const int*)proj)[base];
  }
  __syncthreads();

  // ---- gather + fused L1: H1 = relu(L1pre[id] + rel . W1rel), fp32 math ----
  {
    const int row = tid & 63, part = tid >> 6;
    const int id = sm.sidx[row];
    const long long g = (long long)bid * QB + (row >> 4);
    const int b = (int)(g / NQ);
    const int nq = (int)(g - (long long)b * NQ);
    float rel[3];
#pragma unroll
    for (int j = 0; j < 3; ++j)
      rel[j] = ptsq[((size_t)b * 3 + j) * NQ + nq]
             - pts[((size_t)b * 3 + j) * N + id];
    const _Float16* lp = (const _Float16*)L1pre + ((size_t)b * N + id) * NLAT + part * 64;
    const float* wr0 = w1rT + part * 64;
    const float* wr1 = w1rT + 256 + part * 64;
    const float* wr2 = w1rT + 512 + part * 64;
    char* dst = (char*)sm.buf + row * 528 + part * 128;
#pragma unroll
    for (int cc = 0; cc < 8; ++cc) {
      f16x8 v = *(const f16x8*)(lp + cc * 8);
      const float4 a0 = *(const float4*)(wr0 + cc * 8), a1 = *(const float4*)(wr0 + cc * 8 + 4);
      const float4 b0 = *(const float4*)(wr1 + cc * 8), b1_ = *(const float4*)(wr1 + cc * 8 + 4);
      const float4 c0 = *(const float4*)(wr2 + cc * 8), c1 = *(const float4*)(wr2 + cc * 8 + 4);
      const float wa[8] = {a0.x, a0.y, a0.z, a0.w, a1.x, a1.y, a1.z, a1.w};
      const float wb[8] = {b0.x, b0.y, b0.z, b0.w, b1_.x, b1_.y, b1_.z, b1_.w};
      const float wc[8] = {c0.x, c0.y, c0.z, c0.w, c1.x, c1.y, c1.z, c1.w};
      f16x8 o;
#pragma unroll
      for (int e = 0; e < 8; ++e) {
        float x = (float)v[e] + rel[0] * wa[e] + rel[1] * wb[e] + rel[2] * wc[e];
        o[e] = (_Float16)fmaxf(x, 0.f);
      }
      *(f16x8*)(dst + cc * 16) = o;
    }
  }
  __syncthreads();

  layer_mfma32(sm.buf, W2p, b2, lane, wave, true);   // H2
  __syncthreads();
  layer_mfma32(sm.buf, W3p, b3, lane, wave, true);   // H3
  __syncthreads();

  // ---- Q heads (r6 epilogue): wave owns 16 heads x all 64 rows ----
  const char* bp16 = (const char*)sm.buf + lm * 528 + lk * 16;
  f32x4 qacc[4];
#pragma unroll
  for (int mt = 0; mt < 4; ++mt) qacc[mt] = (f32x4){0.f, 0.f, 0.f, 0.f};
  {
    const char* wqb = (const char*)Wqh + (wave * 16 + lm) * 512 + lk * 16;
#pragma unroll
    for (int ks = 0; ks < 8; ++ks) {
      f16x8 a = *(const f16x8*)(wqb + ks * 64);
#pragma unroll
      for (int mt = 0; mt < 4; ++mt) {
        f16x8 bf = *(const f16x8*)(bp16 + mt * 8448 + ks * 64);
        qacc[mt] = __builtin_amdgcn_mfma_f32_16x16x32_f16(a, bf, qacc[mt], 0, 0, 0);
      }
    }
  }
  // ---- S[row] = wv8 . H3[row] for row = wave*16+lm ----
  {
    const char* sp = (const char*)sm.buf + (wave * 16 + lm) * 528 + lk * 16;
    float sacc = 0.f;
#pragma unroll
    for (int cc = 0; cc < 8; ++cc) {
      f16x8 v = *(const f16x8*)(sp + cc * 64);
      const int k0 = cc * 32 + lk * 8;
      const float4 w0 = *(const float4*)(wv8 + k0);
      const float4 w1 = *(const float4*)(wv8 + k0 + 4);
      sacc += (float)v[0] * w0.x + (float)v[1] * w0.y
            + (float)v[2] * w0.z + (float)v[3] * w0.w;
      sacc += (float)v[4] * w1.x + (float)v[5] * w1.y
            + (float)v[6] * w1.z + (float)v[7] * w1.w;
    }
    sacc += __shfl_xor(sacc, 16);
    sacc += __shfl_xor(sacc, 32);
    if (lk == 0) sm.Sv[wave * 16 + lm] = sacc;
  }

  // ---- softmax over nb (= lm lanes) per head; partial head-sums -> Sp ----
  {
    float bqv[4];
#pragma unroll
    for (int r = 0; r < 4; ++r) bqv[r] = bq[wave * 16 + lk * 4 + r];
#pragma unroll
    for (int mt = 0; mt < 4; ++mt) {
      float sw = 0.f;
#pragma unroll
      for (int r = 0; r < 4; ++r) {
        const float qv = qacc[mt][r] + bqv[r];
        float mx = qv;
#pragma unroll
        for (int msk = 1; msk < 16; msk <<= 1) mx = fmaxf(mx, __shfl_xor(mx, msk));
        const float e = __expf(qv - mx);
        float s = e;
#pragma unroll
        for (int msk = 1; msk < 16; msk <<= 1) s += __shfl_xor(s, msk);
        sw += e / s;
      }
      sw += __shfl_xor(sw, 16);
      sw += __shfl_xor(sw, 32);
      if (lk == 0) sm.Sp[wave][mt * 16 + lm] = sw;
    }
  }
  __syncthreads();

  // ---- out[q] = sum_nb att[m]*S[m] + c0; wave w handles q = w ----
  {
    const int m = wave * 16 + lm;
    const float a = (sm.Sp[0][m] + sm.Sp[1][m] + sm.Sp[2][m] + sm.Sp[3][m]) * (1.f / 64.f);
    float val = a * sm.Sv[m];
#pragma unroll
    for (int msk = 1; msk < 16; msk <<= 1) val += __shfl_xor(val, msk);
    if (lane == 0) out[(long long)bid * QB + wave] = val + c0p[0];
  }
}

// ---- l1pre: L1pre[b][n][ch] = sum_k W1[ch][k]*latent[b][n][k] + b1[ch] ----
// (no relu, no rel). Same tile structure as the main layer; C -> global.
extern "C" __global__ __launch_bounds__(256, 4)
void l1pre_k(const unsigned short* __restrict__ Lt_u,  // fp16 [B][N][256]
             const float* __restrict__ latents,        // fp32 [B][256][N]
             const unsigned short* __restrict__ W1p,
             const float* __restrict__ b1,
             unsigned short* __restrict__ L1pre, int N, int use_lt)
{
  __shared__ unsigned char buf[MROWS * ROWB];
  const int tid = threadIdx.x;
  const int b = blockIdx.y, n0 = blockIdx.x * 64;
  const int lane = tid & 63, wave = tid >> 6;
  const int lm32 = lane & 31, h = lane >> 5;

  {  // stage 64 point-rows
    const int row = tid & 63, part = tid >> 6;
    const int n = n0 + row;
    char* dst = (char*)buf + row * 528 + part * 128;
    if (n < N) {
      if (use_lt) {
        const _Float16* src = (const _Float16*)Lt_u + ((size_t)b * N + n) * NLAT + part * 64;
#pragma unroll
        for (int cc = 0; cc < 8; ++cc)
          *(f16x8*)(dst + cc * 16) = *(const f16x8*)(src + cc * 8);
      } else {
        for (int cc = 0; cc < 8; ++cc) {
          f16x8 v;
#pragma unroll
          for (int e = 0; e < 8; ++e)
            v[e] = (_Float16)latents[((size_t)b * NLAT + part * 64 + cc * 8 + e) * N + n];
          *(f16x8*)(dst + cc * 16) = v;
        }
      }
    } else {
      const f16x8 z = {0, 0, 0, 0, 0, 0, 0, 0};
#pragma unroll
      for (int cc = 0; cc < 8; ++cc) *(f16x8*)(dst + cc * 16) = z;
    }
  }
  __syncthreads();

  const char* bp = (const char*)buf + lm32 * 528 + h * 16;
  const char* wbase = (const char*)W1p + (wave * 64 + lm32) * 32 + h * 16;
  f32x16 acc[2][2];
#pragma unroll
  for (int i = 0; i < 2; ++i)
#pragma unroll
    for (int j = 0; j < 2; ++j) acc[i][j] = (f32x16)(0.f);
#pragma unroll
  for (int ks = 0; ks < 16; ++ks) {
    f16x8 a[2], bb[2];
#pragma unroll
    for (int ct = 0; ct < 2; ++ct)
      a[ct] = *(const f16x8*)(wbase + ks * 8192 + ct * 1024);
#pragma unroll
    for (int mt = 0; mt < 2; ++mt)
      bb[mt] = *(const f16x8*)(bp + mt * MTSTR + ks * 32);
#pragma unroll
    for (int ct = 0; ct < 2; ++ct)
#pragma unroll
      for (int mt = 0; mt < 2; ++mt)
        acc[ct][mt] = __builtin_amdgcn_mfma_f32_32x32x16_f16(a[ct], bb[mt], acc[ct][mt], 0, 0, 0);
  }
  // C -> global: col = point mt*32+lm32, ch = wave*64+ct*32+q*8+h*4 (+bias)
#pragma unroll
  for (int ct = 0; ct < 2; ++ct) {
#pragma unroll
    for (int q = 0; q < 4; ++q) {
      const int ch0 = wave * 64 + ct * 32 + q * 8 + h * 4;
      const float4 bs = *(const float4*)(b1 + ch0);
      const float bb[4] = {bs.x, bs.y, bs.z, bs.w};
#pragma unroll
      for (int mt = 0; mt < 2; ++mt) {
        const int n = n0 + mt * 32 + lm32;
        if (n < N) {
          f16x4 v;
#pragma unroll
          for (int j = 0; j < 4; ++j)
            v[j] = (_Float16)(acc[ct][mt][q * 4 + j] + bb[j]);
          *(f16x4*)((char*)L1pre + (((size_t)b * N + n) * NLAT + ch0) * 2) = v;
        }
      }
    }
  }
}

// ---- prep: fp16 packs (W1p first-256-k, W2p, W3p, Wqh), w1rT, wv8, c0 ----
extern "C" __global__ void prep_w(const float* __restrict__ W1, const float* __restrict__ W2,
                                  const float* __restrict__ W3, const float* __restrict__ Wq,
                                  const float* __restrict__ Wv, const float* __restrict__ W8,
                                  const float* __restrict__ bv, const float* __restrict__ b8,
                                  unsigned short* W1p, unsigned short* W2p,
                                  unsigned short* W3p, unsigned short* Wqh,
                                  float* w1rT, float* wv8, float* c0) {
  const int t = blockIdx.x * 256 + threadIdx.x;
  union { _Float16 h; unsigned short u; } cv;
  if (t < 65536) {
    const int ch = t >> 8, k = t & 255;
    const int dst = (k >> 4) * 4096 + ch * 16 + (k & 15);  // 32x32 k-major pack
    cv.h = (_Float16)W1[(size_t)ch * 259 + k]; W1p[dst] = cv.u;
    cv.h = (_Float16)W2[t]; W2p[dst] = cv.u;
    cv.h = (_Float16)W3[t]; W3p[dst] = cv.u;
  }
  if (t < 16384) { cv.h = (_Float16)Wq[t]; Wqh[t] = cv.u; }  // row-major
  if (t < 768) {  // w1rT[j][ch] = W1[ch][256+j]
    const int j = t >> 8, ch = t & 255;
    w1rT[t] = W1[(size_t)ch * 259 + 256 + j];
  }
  if (t < 256) {
    float s = 0.f;
    for (int o = 0; o < 256; ++o) s += Wv[(size_t)o * 256 + t] * W8[o];
    wv8[t] = s;
  }
  if (t == 0) {
    float s = 0.f;
    for (int o = 0; o < 256; ++o) s += bv[o] * W8[o];
    c0[0] = s + b8[0];
  }
}

// ---- transpose latents [B][256][N] -> fp16 [B][N][256] ----
extern "C" __global__ void transp(const float* __restrict__ latents,
                                  unsigned short* __restrict__ Lt, int N) {
  __shared__ unsigned short tile[256][68];
  const int b = blockIdx.y, n0 = blockIdx.x * 64, tid = threadIdx.x;
  const int nl = tid & 63;
  union { _Float16 h; unsigned short u; } cv;
  for (int c = tid >> 6; c < 256; c += 4) {
    const int n = n0 + nl;
    float v = (n < N) ? latents[((size_t)b * NLAT + c) * N + n] : 0.f;
    cv.h = (_Float16)v;
    tile[c][nl] = cv.u;
  }
  __syncthreads();
  const int nr = tid >> 2, cg = (tid & 3) * 64;
  const int n = n0 + nr;
  if (n < N) {
    for (int cc = 0; cc < 64; cc += 8) {
      f16x8 v;
#pragma unroll
      for (int j = 0; j < 8; ++j) {
        union { unsigned short u; _Float16 h; } bk;
        bk.u = tile[cg + cc + j][nr];
        v[j] = bk.h;
      }
      *(f16x8*)((_Float16*)Lt + ((size_t)b * N + n) * NLAT + cg + cc) = v;
    }
  }
}

extern "C" void kernel_launch(void* const* d_in, const int* in_sizes, int n_in,
                              void* d_out, int out_size, void* d_ws, size_t ws_size,
                              hipStream_t stream) {
  (void)n_in; (void)out_size;
  const float* latents = (const float*)d_in[0];
  const float* pts     = (const float*)d_in[1];
  const float* ptsq    = (const float*)d_in[2];
  const void*  proj    = d_in[3];
  const float* W1 = (const float*)d_in[4];  const float* b1 = (const float*)d_in[5];
  const float* W2 = (const float*)d_in[6];  const float* b2 = (const float*)d_in[7];
  const float* W3 = (const float*)d_in[8];  const float* b3 = (const float*)d_in[9];
  const float* Wq = (const float*)d_in[10]; const float* bq = (const float*)d_in[11];
  const float* Wv = (const float*)d_in[12]; const float* bv = (const float*)d_in[13];
  const float* W8 = (const float*)d_in[14]; const float* b8 = (const float*)d_in[15];
  float* out = (float*)d_out;

  const int B  = 2;
  const int N  = in_sizes[1] / (3 * B);   // pts: [B,3,N]
  const int NQ = in_sizes[2] / (3 * B);   // pts_query: [B,3,NQ]

  size_t off = 0;
  auto alloc = [&](size_t bytes) -> char* {
    char* p = (char*)d_ws + off;
    off += (bytes + 255) & ~(size_t)255;
    return p;
  };
  unsigned short* W1p = (unsigned short*)alloc(65536 * 2);
  unsigned short* W2p = (unsigned short*)alloc(65536 * 2);
  unsigned short* W3p = (unsigned short*)alloc(65536 * 2);
  unsigned short* Wqh = (unsigned short*)alloc(16384 * 2);
  float* w1rT = (float*)alloc(768 * 4);
  float* wv8  = (float*)alloc(256 * 4);
  float* c0   = (float*)alloc(4);
  const size_t l1_bytes = (size_t)B * N * NLAT * 2;
  unsigned short* L1pre = (unsigned short*)alloc(l1_bytes);
  unsigned short* Lt = (unsigned short*)((char*)d_ws + off);
  const int use_lt = (off + l1_bytes <= ws_size) ? 1 : 0;  // Lt same size as L1pre

  hipLaunchKernelGGL(prep_w, dim3(256), dim3(256), 0, stream,
                     W1, W2, W3, Wq, Wv, W8, bv, b8, W1p, W2p, W3p, Wqh,
                     w1rT, wv8, c0);
  if (use_lt)
    hipLaunchKernelGGL(transp, dim3((N + 63) / 64, B), dim3(256), 0, stream,
                       latents, Lt, N);
  hipLaunchKernelGGL(l1pre_k, dim3((N + 63) / 64, B), dim3(256), 0, stream,
                     Lt, latents, W1p, b1, L1pre, N, use_lt);
  const int nblocks = (B * NQ + QB - 1) / QB;   // 5000
  hipLaunchKernelGGL(interp_mfma, dim3(nblocks), dim3(256), 0, stream,
                     pts, ptsq, proj, L1pre, w1rT, W2p, W3p, Wqh,
                     b2, b3, bq, wv8, c0, out, N, NQ);
}

// Round 14
// 198.164 us; speedup vs baseline: 1.4571x; 1.0618x over previous
//
#include <hip/hip_runtime.h>
#include <cstdint>
#include <cstddef>

// InterpAttentionKHeadsNet — round 14: prep consolidation.
// r13 won via L1 fold (hot kernel 192->175us, total 210). Gap analysis:
// ~33us is prep overhead (prep_w + transp + l1pre + gaps). transp existed
// only to feed l1pre coalesced rows; l1pre now stages DIRECTLY from fp32
// latents (lane = point index, coalesced dword loads over n) -> transp
// kernel and the 2x10.2MB Lt round-trip deleted. c0 reduction parallelized
// (wave shuffle). interp_mfma is BYTE-IDENTICAL to r13 (frozen: every
// schedule touch r7-r12 regressed).

#define NLAT 256
#define KNB 16
#define QB 4
#define MROWS 64       // QB*KNB rows per block
#define ROWB 528       // 264 f16: 256 ch used + pad
#define MTSTR 16896    // 32*ROWB

typedef float    f32x4  __attribute__((ext_vector_type(4)));
typedef float    f32x16 __attribute__((ext_vector_type(16)));
typedef _Float16 f16x8  __attribute__((ext_vector_type(8)));
typedef _Float16 f16x4  __attribute__((ext_vector_type(4)));

struct Smem {
  unsigned char buf[MROWS * ROWB];  // 33,792 B in-place activations
  float Sp[4][MROWS];
  float Sv[MROWS];
  int sidx[MROWS];
  int is64;
};

// In-place layer (16 ks): wave computes C'[64ch x 64m] via 2x2 tiles of
// 32x32x16. Wp pack: f16 elem = ks*4096 + ch*16 + (k&15).
__device__ __forceinline__ void layer_mfma32(
    unsigned char* __restrict__ buf, const unsigned short* __restrict__ Wp,
    const float* __restrict__ bias, int lane, int wave, bool relu)
{
  const int lm32 = lane & 31, h = lane >> 5;
  const char* bp = (const char*)buf + lm32 * 528 + h * 16;
  const char* wbase = (const char*)Wp + (wave * 64 + lm32) * 32 + h * 16;

  f32x16 acc[2][2];
#pragma unroll
  for (int i = 0; i < 2; ++i)
#pragma unroll
    for (int j = 0; j < 2; ++j) acc[i][j] = (f32x16)(0.f);

#pragma unroll
  for (int ks = 0; ks < 16; ++ks) {
    f16x8 a[2], b[2];
#pragma unroll
    for (int ct = 0; ct < 2; ++ct)
      a[ct] = *(const f16x8*)(wbase + ks * 8192 + ct * 1024);
#pragma unroll
    for (int mt = 0; mt < 2; ++mt)
      b[mt] = *(const f16x8*)(bp + mt * MTSTR + ks * 32);
#pragma unroll
    for (int ct = 0; ct < 2; ++ct)
#pragma unroll
      for (int mt = 0; mt < 2; ++mt)
        acc[ct][mt] = __builtin_amdgcn_mfma_f32_32x32x16_f16(a[ct], b[mt], acc[ct][mt], 0, 0, 0);
  }
  __syncthreads();  // all reads done -> safe to overwrite in place
  // C layout (32x32): col m = lane&31, ch-row = j + 8q + 4h.
#pragma unroll
  for (int ct = 0; ct < 2; ++ct) {
#pragma unroll
    for (int q = 0; q < 4; ++q) {
      const int ch0 = wave * 64 + ct * 32 + q * 8 + h * 4;
      const float4 bs = *(const float4*)(bias + ch0);
      const float bb[4] = {bs.x, bs.y, bs.z, bs.w};
#pragma unroll
      for (int mt = 0; mt < 2; ++mt) {
        f16x4 v;
#pragma unroll
        for (int j = 0; j < 4; ++j) {
          float x = acc[ct][mt][q * 4 + j] + bb[j];
          if (relu) x = fmaxf(x, 0.f);
          v[j] = (_Float16)x;
        }
        *(f16x4*)((char*)buf + (mt * 32 + lm32) * 528 + ch0 * 2) = v;
      }
    }
  }
}

extern "C" __global__ __launch_bounds__(256, 4)
void interp_mfma(const float* __restrict__ pts,
                 const float* __restrict__ ptsq,
                 const void*  __restrict__ proj,
                 const unsigned short* __restrict__ L1pre,  // fp16 [B][N][256]
                 const float* __restrict__ w1rT,            // fp32 [3][256]
                 const unsigned short* __restrict__ W2p,
                 const unsigned short* __restrict__ W3p,
                 const unsigned short* __restrict__ Wqh,    // fp16 [64][256] row-major
                 const float* __restrict__ b2, const float* __restrict__ b3,
                 const float* __restrict__ bq,
                 const float* __restrict__ wv8, const float* __restrict__ c0p,
                 float* __restrict__ out,
                 int N, int NQ)
{
  __shared__ Smem sm;
  const int tid = threadIdx.x;
  const int bid = blockIdx.x;
  const int lane = tid & 63, wave = tid >> 6;
  const int lm = lane & 15, lk = lane >> 4;

  if (tid == 0) {
    const int* p = (const int*)proj;
    int z = 1;
    for (int i = 0; i < 64; ++i) z &= (p[2 * i + 1] == 0);
    sm.is64 = z;
  }
  __syncthreads();
  if (tid < MROWS) {
    long long g = (long long)bid * QB + (tid >> 4);
    long long base = g * KNB + (tid & 15);
    sm.sidx[tid] = sm.is64 ? (int)((const long long*)proj)[base]
                           : ((const int*)proj)[base];
  }
  __syncthreads();

  // ---- gather + fused L1: H1 = relu(L1pre[id] + rel . W1rel), fp32 math ----
  {
    const int row = tid & 63, part = tid >> 6;
    const int id = sm.sidx[row];
    const long long g = (long long)bid * QB + (row >> 4);
    const int b = (int)(g / NQ);
    const int nq = (int)(g - (long long)b * NQ);
    float rel[3];
#pragma unroll
    for (int j = 0; j < 3; ++j)
      rel[j] = ptsq[((size_t)b * 3 + j) * NQ + nq]
             - pts[((size_t)b * 3 + j) * N + id];
    const _Float16* lp = (const _Float16*)L1pre + ((size_t)b * N + id) * NLAT + part * 64;
    const float* wr0 = w1rT + part * 64;
    const float* wr1 = w1rT + 256 + part * 64;
    const float* wr2 = w1rT + 512 + part * 64;
    char* dst = (char*)sm.buf + row * 528 + part * 128;
#pragma unroll
    for (int cc = 0; cc < 8; ++cc) {
      f16x8 v = *(const f16x8*)(lp + cc * 8);
      const float4 a0 = *(const float4*)(wr0 + cc * 8), a1 = *(const float4*)(wr0 + cc * 8 + 4);
      const float4 b0 = *(const float4*)(wr1 + cc * 8), b1_ = *(const float4*)(wr1 + cc * 8 + 4);
      const float4 c0 = *(const float4*)(wr2 + cc * 8), c1 = *(const float4*)(wr2 + cc * 8 + 4);
      const float wa[8] = {a0.x, a0.y, a0.z, a0.w, a1.x, a1.y, a1.z, a1.w};
      const float wb[8] = {b0.x, b0.y, b0.z, b0.w, b1_.x, b1_.y, b1_.z, b1_.w};
      const float wc[8] = {c0.x, c0.y, c0.z, c0.w, c1.x, c1.y, c1.z, c1.w};
      f16x8 o;
#pragma unroll
      for (int e = 0; e < 8; ++e) {
        float x = (float)v[e] + rel[0] * wa[e] + rel[1] * wb[e] + rel[2] * wc[e];
        o[e] = (_Float16)fmaxf(x, 0.f);
      }
      *(f16x8*)(dst + cc * 16) = o;
    }
  }
  __syncthreads();

  layer_mfma32(sm.buf, W2p, b2, lane, wave, true);   // H2
  __syncthreads();
  layer_mfma32(sm.buf, W3p, b3, lane, wave, true);   // H3
  __syncthreads();

  // ---- Q heads (r6 epilogue): wave owns 16 heads x all 64 rows ----
  const char* bp16 = (const char*)sm.buf + lm * 528 + lk * 16;
  f32x4 qacc[4];
#pragma unroll
  for (int mt = 0; mt < 4; ++mt) qacc[mt] = (f32x4){0.f, 0.f, 0.f, 0.f};
  {
    const char* wqb = (const char*)Wqh + (wave * 16 + lm) * 512 + lk * 16;
#pragma unroll
    for (int ks = 0; ks < 8; ++ks) {
      f16x8 a = *(const f16x8*)(wqb + ks * 64);
#pragma unroll
      for (int mt = 0; mt < 4; ++mt) {
        f16x8 bf = *(const f16x8*)(bp16 + mt * 8448 + ks * 64);
        qacc[mt] = __builtin_amdgcn_mfma_f32_16x16x32_f16(a, bf, qacc[mt], 0, 0, 0);
      }
    }
  }
  // ---- S[row] = wv8 . H3[row] for row = wave*16+lm ----
  {
    const char* sp = (const char*)sm.buf + (wave * 16 + lm) * 528 + lk * 16;
    float sacc = 0.f;
#pragma unroll
    for (int cc = 0; cc < 8; ++cc) {
      f16x8 v = *(const f16x8*)(sp + cc * 64);
      const int k0 = cc * 32 + lk * 8;
      const float4 w0 = *(const float4*)(wv8 + k0);
      const float4 w1 = *(const float4*)(wv8 + k0 + 4);
      sacc += (float)v[0] * w0.x + (float)v[1] * w0.y
            + (float)v[2] * w0.z + (float)v[3] * w0.w;
      sacc += (float)v[4] * w1.x + (float)v[5] * w1.y
            + (float)v[6] * w1.z + (float)v[7] * w1.w;
    }
    sacc += __shfl_xor(sacc, 16);
    sacc += __shfl_xor(sacc, 32);
    if (lk == 0) sm.Sv[wave * 16 + lm] = sacc;
  }

  // ---- softmax over nb (= lm lanes) per head; partial head-sums -> Sp ----
  {
    float bqv[4];
#pragma unroll
    for (int r = 0; r < 4; ++r) bqv[r] = bq[wave * 16 + lk * 4 + r];
#pragma unroll
    for (int mt = 0; mt < 4; ++mt) {
      float sw = 0.f;
#pragma unroll
      for (int r = 0; r < 4; ++r) {
        const float qv = qacc[mt][r] + bqv[r];
        float mx = qv;
#pragma unroll
        for (int msk = 1; msk < 16; msk <<= 1) mx = fmaxf(mx, __shfl_xor(mx, msk));
        const float e = __expf(qv - mx);
        float s = e;
#pragma unroll
        for (int msk = 1; msk < 16; msk <<= 1) s += __shfl_xor(s, msk);
        sw += e / s;
      }
      sw += __shfl_xor(sw, 16);
      sw += __shfl_xor(sw, 32);
      if (lk == 0) sm.Sp[wave][mt * 16 + lm] = sw;
    }
  }
  __syncthreads();

  // ---- out[q] = sum_nb att[m]*S[m] + c0; wave w handles q = w ----
  {
    const int m = wave * 16 + lm;
    const float a = (sm.Sp[0][m] + sm.Sp[1][m] + sm.Sp[2][m] + sm.Sp[3][m]) * (1.f / 64.f);
    float val = a * sm.Sv[m];
#pragma unroll
    for (int msk = 1; msk < 16; msk <<= 1) val += __shfl_xor(val, msk);
    if (lane == 0) out[(long long)bid * QB + wave] = val + c0p[0];
  }
}

// ---- l1pre (fused transpose): stage fp32 latents coalesced -> LDS fp16,
// L1pre[b][n][ch] = sum_k W1[ch][k]*latent[b][k][n] + b1[ch] (no relu).
extern "C" __global__ __launch_bounds__(256, 4)
void l1pre_k(const float* __restrict__ latents,        // fp32 [B][256][N]
             const unsigned short* __restrict__ W1p,
             const float* __restrict__ b1,
             unsigned short* __restrict__ L1pre, int N)
{
  __shared__ unsigned char buf[MROWS * ROWB];
  const int tid = threadIdx.x;
  const int b = blockIdx.y, n0 = blockIdx.x * 64;
  const int lane = tid & 63, wave = tid >> 6;
  const int lm32 = lane & 31, h = lane >> 5;

  {  // stage: thread (nl = point, octets j = (tid>>6) + 4*jj) — coalesced over nl
    const int nl = tid & 63;
    const int n = n0 + nl;
    const bool ok = (n < N);
#pragma unroll
    for (int jj = 0; jj < 8; ++jj) {
      const int j = (tid >> 6) + jj * 4;   // channel octet 0..31
      f16x8 v;
#pragma unroll
      for (int e = 0; e < 8; ++e) {
        const float x = ok ? latents[((size_t)b * NLAT + j * 8 + e) * N + n] : 0.f;
        v[e] = (_Float16)x;
      }
      *(f16x8*)((char*)buf + nl * 528 + j * 16) = v;
    }
  }
  __syncthreads();

  const char* bp = (const char*)buf + lm32 * 528 + h * 16;
  const char* wbase = (const char*)W1p + (wave * 64 + lm32) * 32 + h * 16;
  f32x16 acc[2][2];
#pragma unroll
  for (int i = 0; i < 2; ++i)
#pragma unroll
    for (int j = 0; j < 2; ++j) acc[i][j] = (f32x16)(0.f);
#pragma unroll
  for (int ks = 0; ks < 16; ++ks) {
    f16x8 a[2], bb[2];
#pragma unroll
    for (int ct = 0; ct < 2; ++ct)
      a[ct] = *(const f16x8*)(wbase + ks * 8192 + ct * 1024);
#pragma unroll
    for (int mt = 0; mt < 2; ++mt)
      bb[mt] = *(const f16x8*)(bp + mt * MTSTR + ks * 32);
#pragma unroll
    for (int ct = 0; ct < 2; ++ct)
#pragma unroll
      for (int mt = 0; mt < 2; ++mt)
        acc[ct][mt] = __builtin_amdgcn_mfma_f32_32x32x16_f16(a[ct], bb[mt], acc[ct][mt], 0, 0, 0);
  }
  // C -> global: col = point mt*32+lm32, ch = wave*64+ct*32+q*8+h*4 (+bias)
#pragma unroll
  for (int ct = 0; ct < 2; ++ct) {
#pragma unroll
    for (int q = 0; q < 4; ++q) {
      const int ch0 = wave * 64 + ct * 32 + q * 8 + h * 4;
      const float4 bs = *(const float4*)(b1 + ch0);
      const float bb[4] = {bs.x, bs.y, bs.z, bs.w};
#pragma unroll
      for (int mt = 0; mt < 2; ++mt) {
        const int n = n0 + mt * 32 + lm32;
        if (n < N) {
          f16x4 v;
#pragma unroll
          for (int j = 0; j < 4; ++j)
            v[j] = (_Float16)(acc[ct][mt][q * 4 + j] + bb[j]);
          *(f16x4*)((char*)L1pre + (((size_t)b * N + n) * NLAT + ch0) * 2) = v;
        }
      }
    }
  }
}

// ---- prep: fp16 packs, w1rT, wv8, c0 (wave-parallel) ----
extern "C" __global__ void prep_w(const float* __restrict__ W1, const float* __restrict__ W2,
                                  const float* __restrict__ W3, const float* __restrict__ Wq,
                                  const float* __restrict__ Wv, const float* __restrict__ W8,
                                  const float* __restrict__ bv, const float* __restrict__ b8,
                                  unsigned short* W1p, unsigned short* W2p,
                                  unsigned short* W3p, unsigned short* Wqh,
                                  float* w1rT, float* wv8, float* c0) {
  const int t = blockIdx.x * 256 + threadIdx.x;
  union { _Float16 h; unsigned short u; } cv;
  if (t < 65536) {
    const int ch = t >> 8, k = t & 255;
    const int dst = (k >> 4) * 4096 + ch * 16 + (k & 15);  // 32x32 k-major pack
    cv.h = (_Float16)W1[(size_t)ch * 259 + k]; W1p[dst] = cv.u;
    cv.h = (_Float16)W2[t]; W2p[dst] = cv.u;
    cv.h = (_Float16)W3[t]; W3p[dst] = cv.u;
  }
  if (t < 16384) { cv.h = (_Float16)Wq[t]; Wqh[t] = cv.u; }  // row-major
  if (t < 768) {  // w1rT[j][ch] = W1[ch][256+j]
    const int j = t >> 8, ch = t & 255;
    w1rT[t] = W1[(size_t)ch * 259 + 256 + j];
  }
  if (t < 256) {
    float s = 0.f;
    for (int o = 0; o < 256; ++o) s += Wv[(size_t)o * 256 + t] * W8[o];
    wv8[t] = s;
  }
  if (t < 64) {  // c0 = b8 + W8.bv via wave reduce
    float s = 0.f;
#pragma unroll
    for (int i = 0; i < 4; ++i) s += bv[t + 64 * i] * W8[t + 64 * i];
#pragma unroll
    for (int msk = 1; msk < 64; msk <<= 1) s += __shfl_xor(s, msk);
    if (t == 0) c0[0] = s + b8[0];
  }
}

extern "C" void kernel_launch(void* const* d_in, const int* in_sizes, int n_in,
                              void* d_out, int out_size, void* d_ws, size_t ws_size,
                              hipStream_t stream) {
  (void)n_in; (void)out_size; (void)ws_size;
  const float* latents = (const float*)d_in[0];
  const float* pts     = (const float*)d_in[1];
  const float* ptsq    = (const float*)d_in[2];
  const void*  proj    = d_in[3];
  const float* W1 = (const float*)d_in[4];  const float* b1 = (const float*)d_in[5];
  const float* W2 = (const float*)d_in[6];  const float* b2 = (const float*)d_in[7];
  const float* W3 = (const float*)d_in[8];  const float* b3 = (const float*)d_in[9];
  const float* Wq = (const float*)d_in[10]; const float* bq = (const float*)d_in[11];
  const float* Wv = (const float*)d_in[12]; const float* bv = (const float*)d_in[13];
  const float* W8 = (const float*)d_in[14]; const float* b8 = (const float*)d_in[15];
  float* out = (float*)d_out;

  const int B  = 2;
  const int N  = in_sizes[1] / (3 * B);   // pts: [B,3,N]
  const int NQ = in_sizes[2] / (3 * B);   // pts_query: [B,3,NQ]

  size_t off = 0;
  auto alloc = [&](size_t bytes) -> char* {
    char* p = (char*)d_ws + off;
    off += (bytes + 255) & ~(size_t)255;
    return p;
  };
  unsigned short* W1p = (unsigned short*)alloc(65536 * 2);
  unsigned short* W2p = (unsigned short*)alloc(65536 * 2);
  unsigned short* W3p = (unsigned short*)alloc(65536 * 2);
  unsigned short* Wqh = (unsigned short*)alloc(16384 * 2);
  float* w1rT = (float*)alloc(768 * 4);
  float* wv8  = (float*)alloc(256 * 4);
  float* c0   = (float*)alloc(4);
  unsigned short* L1pre = (unsigned short*)alloc((size_t)B * N * NLAT * 2);

  hipLaunchKernelGGL(prep_w, dim3(256), dim3(256), 0, stream,
                     W1, W2, W3, Wq, Wv, W8, bv, b8, W1p, W2p, W3p, Wqh,
                     w1rT, wv8, c0);
  hipLaunchKernelGGL(l1pre_k, dim3((N + 63) / 64, B), dim3(256), 0, stream,
                     latents, W1p, b1, L1pre, N);
  const int nblocks = (B * NQ + QB - 1) / QB;   // 5000
  hipLaunchKernelGGL(interp_mfma, dim3(nblocks), dim3(256), 0, stream,
                     pts, ptsq, proj, L1pre, w1rT, W2p, W3p, Wqh,
                     b2, b3, bq, wv8, c0, out, N, NQ);
}